// Round 1
// baseline (280.105 us; speedup 1.0000x reference)
//
#include <hip/hip_runtime.h>
#include <stdint.h>

#define NB 64
#define NT 512
#define NH 768
#define NS 128
#define NM (NB*NS)   // 8192 rows

typedef __attribute__((ext_vector_type(8))) short short8;
typedef __attribute__((ext_vector_type(8))) unsigned short ushort8;
typedef __attribute__((ext_vector_type(4))) float f32x4;

__device__ __forceinline__ unsigned short f2bf(float f) {
  unsigned int u = __float_as_uint(f);
  u += 0x7fffu + ((u >> 16) & 1u);   // RNE
  return (unsigned short)(u >> 16);
}
__device__ __forceinline__ float bf2f(unsigned short h) {
  return __uint_as_float(((unsigned int)h) << 16);
}
__device__ __forceinline__ float gelu_exact(float x) {
  return 0.5f * x * (1.0f + erff(x * 0.70710678118654752440f));
}

// async global->LDS, 16B per lane; LDS dest is wave-uniform base (HW adds lane*16)
__device__ __forceinline__ void gll16(const void* g, void* l) {
  __builtin_amdgcn_global_load_lds(
      (__attribute__((address_space(1))) unsigned int*)g,
      (__attribute__((address_space(3))) unsigned int*)l,
      16, 0, 0);
}

// ---------------------------------------------------------------------------
// Weight prep: w[k][n] f32 -> Wt[n][k] bf16 hi/lo, pre-swizzled (elem k ^ ((n&7)<<3))
// covers w1 (slot 0) and w2 (slot 1)
// ---------------------------------------------------------------------------
__global__ void prep_w_kernel(const float* __restrict__ w1, const float* __restrict__ w2,
                              unsigned short* __restrict__ Whi, unsigned short* __restrict__ Wlo) {
  int id = blockIdx.x * 256 + threadIdx.x;   // 2*96*768 total
  int n  = id % NH;
  int t  = id / NH;
  int kc = t % 96;
  int w  = t / 96;
  const float* src = w ? w2 : w1;
  int k0 = kc * 8;
  ushort8 hi, lo;
#pragma unroll
  for (int i = 0; i < 8; ++i) {
    float v = src[(size_t)(k0 + i) * NH + n];   // coalesced across n
    unsigned short h = f2bf(v);
    hi[i] = h;
    lo[i] = f2bf(v - bf2f(h));
  }
  size_t base = (size_t)w * NH * NH + (size_t)n * NH + (size_t)(k0 ^ ((n & 7) << 3));
  *(ushort8*)(Whi + base) = hi;
  *(ushort8*)(Wlo + base) = lo;
}

// ---------------------------------------------------------------------------
// Segment-mean pooling: hidden [B,T,H] f32, sid [B,T] sorted -> A [8192][768]
// bf16 hi/lo, pre-swizzled. Zero-count statements -> zeros (matches reference).
// ---------------------------------------------------------------------------
__global__ void pool_kernel(const float* __restrict__ hidden, const int* __restrict__ sid,
                            unsigned short* __restrict__ Ahi, unsigned short* __restrict__ Alo) {
  int m = blockIdx.x;            // b*128 + s
  int b = m >> 7, s = m & 127;
  const int* row = sid + b * NT;
  int lo = 0, hi = NT;
  while (lo < hi) { int mid = (lo + hi) >> 1; if (row[mid] < s) lo = mid + 1; else hi = mid; }
  int e0 = lo;
  hi = NT;
  while (lo < hi) { int mid = (lo + hi) >> 1; if (row[mid] < s + 1) lo = mid + 1; else hi = mid; }
  int e1 = lo;
  int cnt = e1 - e0;
  float fcnt = (cnt > 0) ? (float)cnt : 1.0f;
  const float* hb = hidden + (size_t)b * NT * NH;
  int xorv = (m & 7) << 3;
  for (int c = threadIdx.x; c < NH; c += 256) {
    float sum = 0.f;
    for (int t = e0; t < e1; ++t) sum += hb[(size_t)t * NH + c];  // coalesced
    float v = sum / fcnt;
    unsigned short h = f2bf(v);
    unsigned short l = f2bf(v - bf2f(h));
    size_t off = (size_t)m * NH + (size_t)(c ^ xorv);
    Ahi[off] = h;
    Alo[off] = l;
  }
}

__global__ void init_logits_kernel(float* __restrict__ logits, const float* __restrict__ b3) {
  int i = blockIdx.x * 256 + threadIdx.x;
  if (i < NM) logits[i] = b3[0];
}
__global__ void sigmoid_kernel(const float* __restrict__ logits, float* __restrict__ out) {
  int i = blockIdx.x * 256 + threadIdx.x;
  if (i < NM) out[i] = 1.0f / (1.0f + expf(-logits[i]));
}

// ---------------------------------------------------------------------------
// bf16x3 GEMM, 128x128 tile, BK=64, 4 waves (2x2), 16x16x32 MFMA.
// A: [M][768] swizzled hi/lo.  B: [N][K] (transposed weights) swizzled hi/lo.
// EPI==0: C = gelu(A@B^T + bias) -> hi/lo swizzled store (input of next layer)
// EPI==1: per-row dot(gelu(..), w3) -> atomicAdd into logits
// ---------------------------------------------------------------------------
template <int EPI>
__global__ __launch_bounds__(256, 2)
void gemm_kernel(const unsigned short* __restrict__ Ahi, const unsigned short* __restrict__ Alo,
                 const unsigned short* __restrict__ Bhi, const unsigned short* __restrict__ Blo,
                 const float* __restrict__ bias,
                 unsigned short* __restrict__ Chi, unsigned short* __restrict__ Clo,
                 const float* __restrict__ w3, float* __restrict__ logits) {
  __shared__ unsigned short lds[4 * 8192];   // Ahi|Alo|Bhi|Blo tiles, each [128][64] = 16KB

  const int tid  = threadIdx.x;
  const int lane = tid & 63;
  const int wave = tid >> 6;
  const int wr = wave >> 1, wc = wave & 1;
  const int mb = blockIdx.y, nb = blockIdx.x;
  const int row0 = mb * 128, col0 = nb * 128;

  const int lr = lane & 15, lk = lane >> 4;
  const int xorv = (lr & 7) << 3;            // swizzle for fragment reads

  // staging geometry: chunk c covers rows c*8..c*8+7 of the tile (1KB per wave-op)
  const int sr = lane >> 3;                  // 0..7
  const int sc = (lane & 7) * 8;             // element col, step 8 (16B)

  f32x4 acc[4][4] = {};

  for (int kt = 0; kt < NH / 64; ++kt) {
    const int kb = kt * 64;
#pragma unroll
    for (int i = 0; i < 4; ++i) {
      const int chunk = i * 4 + wave;        // 0..15
      const int r = chunk * 8 + sr;
      const size_t ga = (size_t)(row0 + r) * NH + kb + sc;
      const size_t gb = (size_t)(col0 + r) * NH + kb + sc;
      gll16(Ahi + ga, &lds[0 * 8192 + chunk * 512]);
      gll16(Alo + ga, &lds[1 * 8192 + chunk * 512]);
      gll16(Bhi + gb, &lds[2 * 8192 + chunk * 512]);
      gll16(Blo + gb, &lds[3 * 8192 + chunk * 512]);
    }
    __syncthreads();   // compiler drains vmcnt before s_barrier

#pragma unroll
    for (int kk = 0; kk < 2; ++kk) {
      const int kl = (kk * 32 + lk * 8) ^ xorv;
      short8 ah[4], al[4], bh[4], bl[4];
#pragma unroll
      for (int f = 0; f < 4; ++f) {
        const int ra = (wr * 64 + f * 16 + lr) * 64 + kl;
        ah[f] = *(const short8*)&lds[0 * 8192 + ra];
        al[f] = *(const short8*)&lds[1 * 8192 + ra];
        const int rb = (wc * 64 + f * 16 + lr) * 64 + kl;
        bh[f] = *(const short8*)&lds[2 * 8192 + rb];
        bl[f] = *(const short8*)&lds[3 * 8192 + rb];
      }
#pragma unroll
      for (int mf = 0; mf < 4; ++mf)
#pragma unroll
        for (int nf = 0; nf < 4; ++nf) {
          acc[mf][nf] = __builtin_amdgcn_mfma_f32_16x16x32_bf16(ah[mf], bh[nf], acc[mf][nf], 0, 0, 0);
          acc[mf][nf] = __builtin_amdgcn_mfma_f32_16x16x32_bf16(ah[mf], bl[nf], acc[mf][nf], 0, 0, 0);
          acc[mf][nf] = __builtin_amdgcn_mfma_f32_16x16x32_bf16(al[mf], bh[nf], acc[mf][nf], 0, 0, 0);
        }
    }
    __syncthreads();
  }

  // epilogue. C/D layout: col = lane&15, row = (lane>>4)*4 + reg  [m89-verified]
  if (EPI == 0) {
#pragma unroll
    for (int nf = 0; nf < 4; ++nf) {
      const int col = col0 + wc * 64 + nf * 16 + lr;
      const float bv = bias[col];
#pragma unroll
      for (int mf = 0; mf < 4; ++mf) {
#pragma unroll
        for (int r = 0; r < 4; ++r) {
          const int rowm = row0 + wr * 64 + mf * 16 + lk * 4 + r;
          float g = gelu_exact(acc[mf][nf][r] + bv);
          unsigned short h = f2bf(g);
          unsigned short l = f2bf(g - bf2f(h));
          size_t off = (size_t)rowm * NH + (size_t)(col ^ ((rowm & 7) << 3));
          Chi[off] = h;
          Clo[off] = l;
        }
      }
    }
  } else {
    float bv[4], wv[4];
#pragma unroll
    for (int nf = 0; nf < 4; ++nf) {
      const int col = col0 + wc * 64 + nf * 16 + lr;
      bv[nf] = bias[col];
      wv[nf] = w3[col];
    }
#pragma unroll
    for (int mf = 0; mf < 4; ++mf) {
#pragma unroll
      for (int r = 0; r < 4; ++r) {
        float part = 0.f;
#pragma unroll
        for (int nf = 0; nf < 4; ++nf)
          part += gelu_exact(acc[mf][nf][r] + bv[nf]) * wv[nf];
        part += __shfl_xor(part, 1, 16);
        part += __shfl_xor(part, 2, 16);
        part += __shfl_xor(part, 4, 16);
        part += __shfl_xor(part, 8, 16);
        if (lr == 0) {
          const int rowm = row0 + wr * 64 + mf * 16 + lk * 4 + r;
          atomicAdd(&logits[rowm], part);
        }
      }
    }
  }
}

// ---------------------------------------------------------------------------
extern "C" void kernel_launch(void* const* d_in, const int* in_sizes, int n_in,
                              void* d_out, int out_size, void* d_ws, size_t ws_size,
                              hipStream_t stream) {
  (void)in_sizes; (void)n_in; (void)out_size; (void)ws_size;
  const float* hidden = (const float*)d_in[0];
  const int*   sid    = (const int*)d_in[1];
  const float* w1     = (const float*)d_in[2];
  const float* b1     = (const float*)d_in[3];
  const float* w2     = (const float*)d_in[4];
  const float* b2     = (const float*)d_in[5];
  const float* w3     = (const float*)d_in[6];
  const float* b3     = (const float*)d_in[7];
  float* out = (float*)d_out;

  char* p = (char*)d_ws;
  const size_t actMB = (size_t)NM * NH * 2;      // 12.58 MB per buffer
  const size_t wMB   = (size_t)2 * NH * NH * 2;  // both weights, one precision
  unsigned short* Ahi  = (unsigned short*)p; p += actMB;
  unsigned short* Alo  = (unsigned short*)p; p += actMB;
  unsigned short* X1hi = (unsigned short*)p; p += actMB;
  unsigned short* X1lo = (unsigned short*)p; p += actMB;
  unsigned short* Whi  = (unsigned short*)p; p += wMB;
  unsigned short* Wlo  = (unsigned short*)p; p += wMB;
  float* logits = (float*)p; p += (size_t)NM * 4;

  prep_w_kernel<<<2 * 96 * NH / 256, 256, 0, stream>>>(w1, w2, Whi, Wlo);
  pool_kernel<<<NM, 256, 0, stream>>>(hidden, sid, Ahi, Alo);
  init_logits_kernel<<<NM / 256, 256, 0, stream>>>(logits, b3);

  dim3 grid(NH / 128, NM / 128);   // (6, 64)
  gemm_kernel<0><<<grid, 256, 0, stream>>>(Ahi, Alo, Whi, Wlo, b1,
                                           X1hi, X1lo, nullptr, nullptr);
  gemm_kernel<1><<<grid, 256, 0, stream>>>(X1hi, X1lo, Whi + (size_t)NH * NH, Wlo + (size_t)NH * NH, b2,
                                           nullptr, nullptr, w3, logits);
  sigmoid_kernel<<<NM / 256, 256, 0, stream>>>(logits, out);
}